// Round 8
// baseline (635.843 us; speedup 1.0000x reference)
//
#include <hip/hip_runtime.h>

// MPM P2G, quadratic B-spline, 3x3x3 stencil.
// Row-sort + row-owned LDS scatter, v2:
//   1) counting-sort particles by (bx,by) ROW key (16384 keys/timestep)
//   2) one WAVE per output z-row; 4 waves/block; Y in low grid bits so the
//      write stream is address-contiguous. Segment bookkeeping fully in
//      registers via shfl; 12 ds_add per particle into the wave's private
//      2KB LDS row; coalesced write-once flush. No global atomics.
//
// Outputs (concatenated in d_out, fp32):
//   grids [T,G,G,G]   -> d_out[0 .. T*G^3)
//   gdef  [T,G,G,G,3] -> d_out[T*G^3 .. 4*T*G^3)

constexpr int   G      = 128;
constexpr int   CELLS  = G * G * G;
constexpr int   NROWK  = G * G;          // 16384 row keys per timestep
constexpr float MINN   = -15.0f;
constexpr float EXTENT = 40.0f;

__device__ __forceinline__ int3 base_cell(float x, float y, float z,
                                          float& fx, float& fy, float& fz)
{
    const float scale = (float)G / EXTENT;
    const float Xp = (x - MINN) * scale;
    const float Yp = (y - MINN) * scale;
    const float Zp = (z - MINN) * scale;
    int bx = (int)floorf(Xp - 0.5f);
    int by = (int)floorf(Yp - 0.5f);
    int bz = (int)floorf(Zp - 0.5f);
    // f from the UNclamped base (matches reference); clamp affects indices only
    fx = Xp - (float)bx; fy = Yp - (float)by; fz = Zp - (float)bz;
    bx = min(max(bx, 0), G - 3);
    by = min(max(by, 0), G - 3);
    bz = min(max(bz, 0), G - 3);
    return make_int3(bx, by, bz);
}

__device__ __forceinline__ float wsel(float f, int d)
{
    const float r0 = 1.5f - f, r1 = f - 1.0f, r2 = f - 0.5f;
    const float w0 = 0.5f * r0 * r0;
    const float w1 = 0.75f - r1 * r1;
    const float w2 = 0.5f * r2 * r2;
    return d == 0 ? w0 : (d == 1 ? w1 : w2);
}

// ---- K1: histogram by row key -----------------------------------------------
__global__ void __launch_bounds__(256)
row_hist(const float* __restrict__ xs, int* __restrict__ arr, int N)
{
    const int p = blockIdx.x * blockDim.x + threadIdx.x;
    const int t = blockIdx.y;
    if (p >= N) return;
    const long i = (long)t * N + p;
    float fx, fy, fz;
    int3 b = base_cell(xs[i*3], xs[i*3+1], xs[i*3+2], fx, fy, fz);
    atomicAdd(&arr[t * NROWK + (b.x << 7) + b.y], 1);
}

// ---- K2: per-t exclusive scan of 16384 (1 block/t, 256 thr x 64 keys) -------
__global__ void __launch_bounds__(256)
row_scan(int* __restrict__ arr)
{
    const int t = blockIdx.x, tid = threadIdx.x;
    int* a = arr + t * NROWK + tid * 64;
    int s = 0;
    for (int i = 0; i < 64; ++i) s += a[i];
    __shared__ int part[256];
    part[tid] = s;
    __syncthreads();
    const int own = s;
    for (int d = 1; d < 256; d <<= 1) {
        int v = (tid >= d) ? part[tid - d] : 0;
        __syncthreads();
        part[tid] += v;
        __syncthreads();
    }
    int run = part[tid] - own;           // exclusive prefix of this 64-chunk
    for (int i = 0; i < 64; ++i) { const int v = a[i]; a[i] = run; run += v; }
}

// ---- K3: scatter into row-sorted order (arr becomes END offsets) ------------
__global__ void __launch_bounds__(256)
scatter_rows(const float* __restrict__ xs, const float* __restrict__ def,
             int* __restrict__ arr,
             float4* __restrict__ sA, float2* __restrict__ sB, int N)
{
    const int p = blockIdx.x * blockDim.x + threadIdx.x;
    const int t = blockIdx.y;
    if (p >= N) return;
    const long i = (long)t * N + p;
    const float x = xs[i*3], y = xs[i*3+1], z = xs[i*3+2];
    float fx, fy, fz;
    int3 b = base_cell(x, y, z, fx, fy, fz);
    const int slot = atomicAdd(&arr[t * NROWK + (b.x << 7) + b.y], 1);
    const long o = (long)t * N + slot;
    sA[o] = make_float4(x, y, z, def[i*3]);
    sB[o] = make_float2(def[i*3+1], def[i*3+2]);
}

// ---- K4 v2: one WAVE per z-row, 4 waves/block, register bookkeeping ---------
__global__ void __launch_bounds__(256)
p2g_row2(const float4* __restrict__ sA, const float2* __restrict__ sB,
         const int* __restrict__ arr,
         float* __restrict__ grids, float* __restrict__ gdef, int N)
{
    const int wid  = threadIdx.x >> 6;
    const int lane = threadIdx.x & 63;
    const int t    = blockIdx.y;
    const int rowlin = blockIdx.x * 4 + wid;     // Y in LOW bits -> contiguous writes
    const int Y = rowlin & (G - 1);
    const int X = rowlin >> 7;

    __shared__ float smAll[4][4 * G];            // per-wave [comp][z], 8 KB total
    float* sm = smAll[wid];
    #pragma unroll
    for (int i = lane; i < 4 * G; i += 64) sm[i] = 0.0f;

    // segment descriptors in lanes 0..8 (row keys (X-2..X) x (Y-2..Y))
    int beg = 0, cnt = 0;
    if (lane < 9) {
        const int rx = X - 2 + lane / 3;
        const int ry = Y - 2 + lane % 3;
        if (rx >= 0 && rx <= G - 3 && ry >= 0 && ry <= G - 3) {
            const int rk = (rx << 7) + ry;
            const int e  = arr[t * NROWK + rk];
            const int b  = rk ? arr[t * NROWK + rk - 1] : 0;
            beg = b; cnt = e - b;
        }
    }
    // inclusive prefix over lanes 0..8 (shfl, all lanes active here)
    int incl = cnt;
    #pragma unroll
    for (int d = 1; d <= 8; d <<= 1) {
        int v = __shfl_up(incl, d);
        if (lane >= d) incl += v;
    }
    const int excl  = incl - cnt;
    const int total = __shfl(incl, 8);
    const int so1 = __shfl(excl, 1), so2 = __shfl(excl, 2), so3 = __shfl(excl, 3),
              so4 = __shfl(excl, 4), so5 = __shfl(excl, 5), so6 = __shfl(excl, 6),
              so7 = __shfl(excl, 7), so8 = __shfl(excl, 8);
    const int adj  = beg - excl;                 // per-segment: idx = j + adj
    const int adj0 = __shfl(adj, 0), adj1 = __shfl(adj, 1), adj2 = __shfl(adj, 2),
              adj3 = __shfl(adj, 3), adj4 = __shfl(adj, 4), adj5 = __shfl(adj, 5),
              adj6 = __shfl(adj, 6), adj7 = __shfl(adj, 7), adj8 = __shfl(adj, 8);
    const long pbase = (long)t * N;

    for (int j = lane; j < total; j += 64) {     // typically ONE iteration
        const int g1 = (j >= so1), g2 = (j >= so2), g3 = (j >= so3), g4 = (j >= so4),
                  g5 = (j >= so5), g6 = (j >= so6), g7 = (j >= so7), g8 = (j >= so8);
        const int r = g1 + g2 + g3 + g4 + g5 + g6 + g7 + g8;
        int a = adj0;
        a = g1 ? adj1 : a;  a = g2 ? adj2 : a;  a = g3 ? adj3 : a;  a = g4 ? adj4 : a;
        a = g5 ? adj5 : a;  a = g6 ? adj6 : a;  a = g7 ? adj7 : a;  a = g8 ? adj8 : a;
        const int idx = j + a;

        const float4 A = sA[pbase + idx];
        const float2 B = sB[pbase + idx];
        float fx, fy, fz;
        const int3 b = base_cell(A.x, A.y, A.z, fx, fy, fz);
        const float wxy = wsel(fx, 2 - r / 3) * wsel(fy, 2 - r % 3);

        const float q0 = 1.5f - fz, q1 = fz - 1.0f, q2 = fz - 0.5f;
        const float w0 = wxy * (0.5f * q0 * q0);
        const float w1 = wxy * (0.75f - q1 * q1);
        const float w2 = wxy * (0.5f * q2 * q2);

        const int z = b.z;                       // z..z+2 <= 127
        atomicAdd(&sm[z        ], w0);           // P_MASS = 1
        atomicAdd(&sm[z + 1    ], w1);
        atomicAdd(&sm[z + 2    ], w2);
        atomicAdd(&sm[G + z    ], w0 * A.w);
        atomicAdd(&sm[G + z + 1], w1 * A.w);
        atomicAdd(&sm[G + z + 2], w2 * A.w);
        atomicAdd(&sm[2*G + z    ], w0 * B.x);
        atomicAdd(&sm[2*G + z + 1], w1 * B.x);
        atomicAdd(&sm[2*G + z + 2], w2 * B.x);
        atomicAdd(&sm[3*G + z    ], w0 * B.y);
        atomicAdd(&sm[3*G + z + 1], w1 * B.y);
        atomicAdd(&sm[3*G + z + 2], w2 * B.y);
    }
    __syncthreads();                             // LDS visibility before flush

    // flush: wave owns the whole (t,X,Y,*) row -> plain coalesced stores
    const long cbase = (long)t * CELLS + ((long)rowlin << 7);
    grids[cbase + lane]      = sm[lane];
    grids[cbase + 64 + lane] = sm[64 + lane];
    float* grow = gdef + cbase * 3;              // 384 contiguous floats
    #pragma unroll
    for (int i = lane; i < 3 * G; i += 64)
        grow[i] = sm[(1 + i % 3) * G + i / 3];   // const div/mod -> magic mul
}

// ---- last-resort fallback: direct global atomics ----------------------------
__global__ void __launch_bounds__(256)
p2g_direct(const float* __restrict__ xs, const float* __restrict__ def,
           float* __restrict__ grids, float* __restrict__ gdef, int N)
{
    const int p = blockIdx.x * blockDim.x + threadIdx.x;
    const int t = blockIdx.y;
    if (p >= N) return;
    const long i = (long)t * N + p;
    const float dx = def[i*3], dy = def[i*3+1], dz = def[i*3+2];
    float fx, fy, fz;
    int3 b = base_cell(xs[i*3], xs[i*3+1], xs[i*3+2], fx, fy, fz);
    float wx[3], wy[3], wz[3];
    wx[0] = 0.5f*(1.5f-fx)*(1.5f-fx); wx[1] = 0.75f-(fx-1.f)*(fx-1.f); wx[2] = 0.5f*(fx-0.5f)*(fx-0.5f);
    wy[0] = 0.5f*(1.5f-fy)*(1.5f-fy); wy[1] = 0.75f-(fy-1.f)*(fy-1.f); wy[2] = 0.5f*(fy-0.5f)*(fy-0.5f);
    wz[0] = 0.5f*(1.5f-fz)*(1.5f-fz); wz[1] = 0.75f-(fz-1.f)*(fz-1.f); wz[2] = 0.5f*(fz-0.5f)*(fz-0.5f);
    const long tbase = (long)t * CELLS;
    #pragma unroll
    for (int ii = 0; ii < 3; ++ii) {
        const long xoff = tbase + (long)(b.x + ii) * (G * G);
        #pragma unroll
        for (int jj = 0; jj < 3; ++jj) {
            const float wij = wx[ii] * wy[jj];
            const long yoff = xoff + (long)(b.y + jj) * G;
            #pragma unroll
            for (int kk = 0; kk < 3; ++kk) {
                const float w = wij * wz[kk];
                const long idx = yoff + (b.z + kk);
                atomicAdd(&grids[idx], w);
                atomicAdd(&gdef[idx*3+0], w * dx);
                atomicAdd(&gdef[idx*3+1], w * dy);
                atomicAdd(&gdef[idx*3+2], w * dz);
            }
        }
    }
}

extern "C" void kernel_launch(void* const* d_in, const int* in_sizes, int n_in,
                              void* d_out, int out_size, void* d_ws, size_t ws_size,
                              hipStream_t stream)
{
    const float* xs  = (const float*)d_in[0];
    const float* def = (const float*)d_in[1];
    float* out = (float*)d_out;

    const int T = (int)(out_size / ((long)CELLS * 4));
    const int N = in_sizes[0] / (3 * T);

    float* grids = out;
    float* gdef  = out + (long)T * CELLS;

    const size_t szA   = (size_t)T * N * sizeof(float4);
    const size_t szB   = (size_t)T * N * sizeof(float2);
    const size_t szArr = (size_t)T * NROWK * sizeof(int);    // 512 KB
    const size_t need  = szA + szB + szArr;

    if (ws_size >= need) {
        char* ws = (char*)d_ws;
        float4* sA  = (float4*)ws;  ws += szA;
        float2* sB  = (float2*)ws;  ws += szB;
        int*    arr = (int*)ws;

        hipMemsetAsync(arr, 0, szArr, stream);

        dim3 pgrid((N + 255) / 256, T);
        row_hist    <<<pgrid, dim3(256), 0, stream>>>(xs, arr, N);
        row_scan    <<<dim3(T), dim3(256), 0, stream>>>(arr);
        scatter_rows<<<pgrid, dim3(256), 0, stream>>>(xs, def, arr, sA, sB, N);
        p2g_row2    <<<dim3(NROWK / 4, T), dim3(256), 0, stream>>>(sA, sB, arr,
                                                                   grids, gdef, N);
        return;
    }

    hipMemsetAsync(d_out, 0, (size_t)out_size * sizeof(float), stream);
    dim3 grid((N + 255) / 256, T);
    p2g_direct<<<grid, dim3(256), 0, stream>>>(xs, def, grids, gdef, N);
}

// Round 9
// 635.664 us; speedup vs baseline: 1.0003x; 1.0003x over previous
//
#include <hip/hip_runtime.h>

// MPM P2G, quadratic B-spline, 3x3x3 stencil.
// Row-sort + row-owned LDS scatter, v3 = v2 with HW LDS fp atomics.
// A/B vs round 8: ONLY change is atomicAdd -> unsafeAtomicAdd on LDS
// (default shared-float atomicAdd compiles to a CAS retry loop; theory is
// that loop is the shared ~530us floor of all LDS-scatter variants).
//
// Outputs (concatenated in d_out, fp32):
//   grids [T,G,G,G]   -> d_out[0 .. T*G^3)
//   gdef  [T,G,G,G,3] -> d_out[T*G^3 .. 4*T*G^3)

constexpr int   G      = 128;
constexpr int   CELLS  = G * G * G;
constexpr int   NROWK  = G * G;          // 16384 row keys per timestep
constexpr float MINN   = -15.0f;
constexpr float EXTENT = 40.0f;

__device__ __forceinline__ int3 base_cell(float x, float y, float z,
                                          float& fx, float& fy, float& fz)
{
    const float scale = (float)G / EXTENT;
    const float Xp = (x - MINN) * scale;
    const float Yp = (y - MINN) * scale;
    const float Zp = (z - MINN) * scale;
    int bx = (int)floorf(Xp - 0.5f);
    int by = (int)floorf(Yp - 0.5f);
    int bz = (int)floorf(Zp - 0.5f);
    // f from the UNclamped base (matches reference); clamp affects indices only
    fx = Xp - (float)bx; fy = Yp - (float)by; fz = Zp - (float)bz;
    bx = min(max(bx, 0), G - 3);
    by = min(max(by, 0), G - 3);
    bz = min(max(bz, 0), G - 3);
    return make_int3(bx, by, bz);
}

__device__ __forceinline__ float wsel(float f, int d)
{
    const float r0 = 1.5f - f, r1 = f - 1.0f, r2 = f - 0.5f;
    const float w0 = 0.5f * r0 * r0;
    const float w1 = 0.75f - r1 * r1;
    const float w2 = 0.5f * r2 * r2;
    return d == 0 ? w0 : (d == 1 ? w1 : w2);
}

// ---- K1: histogram by row key -----------------------------------------------
__global__ void __launch_bounds__(256)
row_hist(const float* __restrict__ xs, int* __restrict__ arr, int N)
{
    const int p = blockIdx.x * blockDim.x + threadIdx.x;
    const int t = blockIdx.y;
    if (p >= N) return;
    const long i = (long)t * N + p;
    float fx, fy, fz;
    int3 b = base_cell(xs[i*3], xs[i*3+1], xs[i*3+2], fx, fy, fz);
    atomicAdd(&arr[t * NROWK + (b.x << 7) + b.y], 1);
}

// ---- K2: per-t exclusive scan of 16384 (1 block/t, 256 thr x 64 keys) -------
__global__ void __launch_bounds__(256)
row_scan(int* __restrict__ arr)
{
    const int t = blockIdx.x, tid = threadIdx.x;
    int* a = arr + t * NROWK + tid * 64;
    int s = 0;
    for (int i = 0; i < 64; ++i) s += a[i];
    __shared__ int part[256];
    part[tid] = s;
    __syncthreads();
    const int own = s;
    for (int d = 1; d < 256; d <<= 1) {
        int v = (tid >= d) ? part[tid - d] : 0;
        __syncthreads();
        part[tid] += v;
        __syncthreads();
    }
    int run = part[tid] - own;           // exclusive prefix of this 64-chunk
    for (int i = 0; i < 64; ++i) { const int v = a[i]; a[i] = run; run += v; }
}

// ---- K3: scatter into row-sorted order (arr becomes END offsets) ------------
__global__ void __launch_bounds__(256)
scatter_rows(const float* __restrict__ xs, const float* __restrict__ def,
             int* __restrict__ arr,
             float4* __restrict__ sA, float2* __restrict__ sB, int N)
{
    const int p = blockIdx.x * blockDim.x + threadIdx.x;
    const int t = blockIdx.y;
    if (p >= N) return;
    const long i = (long)t * N + p;
    const float x = xs[i*3], y = xs[i*3+1], z = xs[i*3+2];
    float fx, fy, fz;
    int3 b = base_cell(x, y, z, fx, fy, fz);
    const int slot = atomicAdd(&arr[t * NROWK + (b.x << 7) + b.y], 1);
    const long o = (long)t * N + slot;
    sA[o] = make_float4(x, y, z, def[i*3]);
    sB[o] = make_float2(def[i*3+1], def[i*3+2]);
}

// ---- K4 v3: one WAVE per z-row, HW ds_add_f32 via unsafeAtomicAdd -----------
__global__ void __launch_bounds__(256)
p2g_row2(const float4* __restrict__ sA, const float2* __restrict__ sB,
         const int* __restrict__ arr,
         float* __restrict__ grids, float* __restrict__ gdef, int N)
{
    const int wid  = threadIdx.x >> 6;
    const int lane = threadIdx.x & 63;
    const int t    = blockIdx.y;
    const int rowlin = blockIdx.x * 4 + wid;     // Y in LOW bits -> contiguous writes
    const int Y = rowlin & (G - 1);
    const int X = rowlin >> 7;

    __shared__ float smAll[4][4 * G];            // per-wave [comp][z], 8 KB total
    float* sm = smAll[wid];
    #pragma unroll
    for (int i = lane; i < 4 * G; i += 64) sm[i] = 0.0f;

    // segment descriptors in lanes 0..8 (row keys (X-2..X) x (Y-2..Y))
    int beg = 0, cnt = 0;
    if (lane < 9) {
        const int rx = X - 2 + lane / 3;
        const int ry = Y - 2 + lane % 3;
        if (rx >= 0 && rx <= G - 3 && ry >= 0 && ry <= G - 3) {
            const int rk = (rx << 7) + ry;
            const int e  = arr[t * NROWK + rk];
            const int b  = rk ? arr[t * NROWK + rk - 1] : 0;
            beg = b; cnt = e - b;
        }
    }
    // inclusive prefix over lanes 0..8 (shfl, all lanes active here)
    int incl = cnt;
    #pragma unroll
    for (int d = 1; d <= 8; d <<= 1) {
        int v = __shfl_up(incl, d);
        if (lane >= d) incl += v;
    }
    const int excl  = incl - cnt;
    const int total = __shfl(incl, 8);
    const int so1 = __shfl(excl, 1), so2 = __shfl(excl, 2), so3 = __shfl(excl, 3),
              so4 = __shfl(excl, 4), so5 = __shfl(excl, 5), so6 = __shfl(excl, 6),
              so7 = __shfl(excl, 7), so8 = __shfl(excl, 8);
    const int adj  = beg - excl;                 // per-segment: idx = j + adj
    const int adj0 = __shfl(adj, 0), adj1 = __shfl(adj, 1), adj2 = __shfl(adj, 2),
              adj3 = __shfl(adj, 3), adj4 = __shfl(adj, 4), adj5 = __shfl(adj, 5),
              adj6 = __shfl(adj, 6), adj7 = __shfl(adj, 7), adj8 = __shfl(adj, 8);
    const long pbase = (long)t * N;

    for (int j = lane; j < total; j += 64) {     // typically ONE iteration
        const int g1 = (j >= so1), g2 = (j >= so2), g3 = (j >= so3), g4 = (j >= so4),
                  g5 = (j >= so5), g6 = (j >= so6), g7 = (j >= so7), g8 = (j >= so8);
        const int r = g1 + g2 + g3 + g4 + g5 + g6 + g7 + g8;
        int a = adj0;
        a = g1 ? adj1 : a;  a = g2 ? adj2 : a;  a = g3 ? adj3 : a;  a = g4 ? adj4 : a;
        a = g5 ? adj5 : a;  a = g6 ? adj6 : a;  a = g7 ? adj7 : a;  a = g8 ? adj8 : a;
        const int idx = j + a;

        const float4 A = sA[pbase + idx];
        const float2 B = sB[pbase + idx];
        float fx, fy, fz;
        const int3 b = base_cell(A.x, A.y, A.z, fx, fy, fz);
        const float wxy = wsel(fx, 2 - r / 3) * wsel(fy, 2 - r % 3);

        const float q0 = 1.5f - fz, q1 = fz - 1.0f, q2 = fz - 0.5f;
        const float w0 = wxy * (0.5f * q0 * q0);
        const float w1 = wxy * (0.75f - q1 * q1);
        const float w2 = wxy * (0.5f * q2 * q2);

        const int z = b.z;                       // z..z+2 <= 127
        unsafeAtomicAdd(&sm[z        ], w0);     // ds_add_f32 (P_MASS = 1)
        unsafeAtomicAdd(&sm[z + 1    ], w1);
        unsafeAtomicAdd(&sm[z + 2    ], w2);
        unsafeAtomicAdd(&sm[G + z    ], w0 * A.w);
        unsafeAtomicAdd(&sm[G + z + 1], w1 * A.w);
        unsafeAtomicAdd(&sm[G + z + 2], w2 * A.w);
        unsafeAtomicAdd(&sm[2*G + z    ], w0 * B.x);
        unsafeAtomicAdd(&sm[2*G + z + 1], w1 * B.x);
        unsafeAtomicAdd(&sm[2*G + z + 2], w2 * B.x);
        unsafeAtomicAdd(&sm[3*G + z    ], w0 * B.y);
        unsafeAtomicAdd(&sm[3*G + z + 1], w1 * B.y);
        unsafeAtomicAdd(&sm[3*G + z + 2], w2 * B.y);
    }
    __syncthreads();                             // LDS visibility before flush

    // flush: wave owns the whole (t,X,Y,*) row -> plain coalesced stores
    const long cbase = (long)t * CELLS + ((long)rowlin << 7);
    grids[cbase + lane]      = sm[lane];
    grids[cbase + 64 + lane] = sm[64 + lane];
    float* grow = gdef + cbase * 3;              // 384 contiguous floats
    #pragma unroll
    for (int i = lane; i < 3 * G; i += 64)
        grow[i] = sm[(1 + i % 3) * G + i / 3];   // const div/mod -> magic mul
}

// ---- last-resort fallback: direct global atomics ----------------------------
__global__ void __launch_bounds__(256)
p2g_direct(const float* __restrict__ xs, const float* __restrict__ def,
           float* __restrict__ grids, float* __restrict__ gdef, int N)
{
    const int p = blockIdx.x * blockDim.x + threadIdx.x;
    const int t = blockIdx.y;
    if (p >= N) return;
    const long i = (long)t * N + p;
    const float dx = def[i*3], dy = def[i*3+1], dz = def[i*3+2];
    float fx, fy, fz;
    int3 b = base_cell(xs[i*3], xs[i*3+1], xs[i*3+2], fx, fy, fz);
    float wx[3], wy[3], wz[3];
    wx[0] = 0.5f*(1.5f-fx)*(1.5f-fx); wx[1] = 0.75f-(fx-1.f)*(fx-1.f); wx[2] = 0.5f*(fx-0.5f)*(fx-0.5f);
    wy[0] = 0.5f*(1.5f-fy)*(1.5f-fy); wy[1] = 0.75f-(fy-1.f)*(fy-1.f); wy[2] = 0.5f*(fy-0.5f)*(fy-0.5f);
    wz[0] = 0.5f*(1.5f-fz)*(1.5f-fz); wz[1] = 0.75f-(fz-1.f)*(fz-1.f); wz[2] = 0.5f*(fz-0.5f)*(fz-0.5f);
    const long tbase = (long)t * CELLS;
    #pragma unroll
    for (int ii = 0; ii < 3; ++ii) {
        const long xoff = tbase + (long)(b.x + ii) * (G * G);
        #pragma unroll
        for (int jj = 0; jj < 3; ++jj) {
            const float wij = wx[ii] * wy[jj];
            const long yoff = xoff + (long)(b.y + jj) * G;
            #pragma unroll
            for (int kk = 0; kk < 3; ++kk) {
                const float w = wij * wz[kk];
                const long idx = yoff + (b.z + kk);
                atomicAdd(&grids[idx], w);
                atomicAdd(&gdef[idx*3+0], w * dx);
                atomicAdd(&gdef[idx*3+1], w * dy);
                atomicAdd(&gdef[idx*3+2], w * dz);
            }
        }
    }
}

extern "C" void kernel_launch(void* const* d_in, const int* in_sizes, int n_in,
                              void* d_out, int out_size, void* d_ws, size_t ws_size,
                              hipStream_t stream)
{
    const float* xs  = (const float*)d_in[0];
    const float* def = (const float*)d_in[1];
    float* out = (float*)d_out;

    const int T = (int)(out_size / ((long)CELLS * 4));
    const int N = in_sizes[0] / (3 * T);

    float* grids = out;
    float* gdef  = out + (long)T * CELLS;

    const size_t szA   = (size_t)T * N * sizeof(float4);
    const size_t szB   = (size_t)T * N * sizeof(float2);
    const size_t szArr = (size_t)T * NROWK * sizeof(int);    // 512 KB
    const size_t need  = szA + szB + szArr;

    if (ws_size >= need) {
        char* ws = (char*)d_ws;
        float4* sA  = (float4*)ws;  ws += szA;
        float2* sB  = (float2*)ws;  ws += szB;
        int*    arr = (int*)ws;

        hipMemsetAsync(arr, 0, szArr, stream);

        dim3 pgrid((N + 255) / 256, T);
        row_hist    <<<pgrid, dim3(256), 0, stream>>>(xs, arr, N);
        row_scan    <<<dim3(T), dim3(256), 0, stream>>>(arr);
        scatter_rows<<<pgrid, dim3(256), 0, stream>>>(xs, def, arr, sA, sB, N);
        p2g_row2    <<<dim3(NROWK / 4, T), dim3(256), 0, stream>>>(sA, sB, arr,
                                                                   grids, gdef, N);
        return;
    }

    hipMemsetAsync(d_out, 0, (size_t)out_size * sizeof(float), stream);
    dim3 grid((N + 255) / 256, T);
    p2g_direct<<<grid, dim3(256), 0, stream>>>(xs, def, grids, gdef, N);
}

// Round 10
// 346.470 us; speedup vs baseline: 1.8352x; 1.8347x over previous
//
#include <hip/hip_runtime.h>

// MPM P2G, quadratic B-spline, 3x3x3 stencil.
// Cell-sort + merged-loop gather (no atomics anywhere in the hot kernel):
//   1) counting-sort particles by clamped base cell (z in low key bits)
//   2) one thread per output cell; its <=9 source-row ranges (z-window
//      contiguous) are MERGED into one loop with a cndmask segment chain
//      -> no per-range divergence, register accumulation, write-once stores.
// HW model (r5/r7/r8/r9): LDS atomic f32 adds serialize ~3.8 cyc/lane-op/CU;
// 86.4M of them floor any scatter design at ~500us. Hence: gather, no atomics.
//
// Outputs (concatenated in d_out, fp32):
//   grids [T,G,G,G]   -> d_out[0 .. T*G^3)
//   gdef  [T,G,G,G,3] -> d_out[T*G^3 .. 4*T*G^3)

constexpr int   G      = 128;
constexpr int   CELLS  = G * G * G;       // 2,097,152
constexpr float MINN   = -15.0f;
constexpr float EXTENT = 40.0f;

__device__ __forceinline__ int3 base_cell(float x, float y, float z,
                                          float& fx, float& fy, float& fz)
{
    const float scale = (float)G / EXTENT;
    const float Xp = (x - MINN) * scale;
    const float Yp = (y - MINN) * scale;
    const float Zp = (z - MINN) * scale;
    int bx = (int)floorf(Xp - 0.5f);
    int by = (int)floorf(Yp - 0.5f);
    int bz = (int)floorf(Zp - 0.5f);
    // f from the UNclamped base (matches reference); clamp affects indices only
    fx = Xp - (float)bx; fy = Yp - (float)by; fz = Zp - (float)bz;
    bx = min(max(bx, 0), G - 3);
    by = min(max(by, 0), G - 3);
    bz = min(max(bz, 0), G - 3);
    return make_int3(bx, by, bz);
}

__device__ __forceinline__ float wsel(float f, int d)
{
    const float r0 = 1.5f - f, r1 = f - 1.0f, r2 = f - 0.5f;
    const float w0 = 0.5f * r0 * r0;
    const float w1 = 0.75f - r1 * r1;
    const float w2 = 0.5f * r2 * r2;
    return d == 0 ? w0 : (d == 1 ? w1 : w2);
}

// ---- K1: per-cell histogram -------------------------------------------------
__global__ void __launch_bounds__(256)
cell_hist(const float* __restrict__ xs, int* __restrict__ arr, int N)
{
    const int p = blockIdx.x * blockDim.x + threadIdx.x;
    const int t = blockIdx.y;
    if (p >= N) return;
    const long i = (long)t * N + p;
    float fx, fy, fz;
    int3 b = base_cell(xs[i*3], xs[i*3+1], xs[i*3+2], fx, fy, fz);
    const int key = (b.x << 14) + (b.y << 7) + b.z;
    atomicAdd(&arr[(long)t * CELLS + key], 1);
}

// ---- K2a: per-4096-chunk exclusive scan (in place) + chunk totals -----------
__global__ void __launch_bounds__(256)
scan1(int* __restrict__ arr, int* __restrict__ sums)
{
    const int t = blockIdx.y, tid = threadIdx.x;
    int* a = arr + (long)t * CELLS + (long)blockIdx.x * 4096 + tid * 16;
    int local[16], s = 0;
    #pragma unroll
    for (int i = 0; i < 16; ++i) { const int v = a[i]; local[i] = s; s += v; }
    __shared__ int part[256];
    part[tid] = s;
    __syncthreads();
    const int own = s;
    for (int d = 1; d < 256; d <<= 1) {
        int v = (tid >= d) ? part[tid - d] : 0;
        __syncthreads();
        part[tid] += v;
        __syncthreads();
    }
    const int excl = part[tid] - own;
    #pragma unroll
    for (int i = 0; i < 16; ++i) a[i] = excl + local[i];
    if (tid == 255) sums[t * 512 + blockIdx.x] = part[255];
}

// ---- K2b: exclusive scan of the 512 chunk totals per timestep ---------------
__global__ void __launch_bounds__(256)
scan2(int* __restrict__ sums)
{
    const int t = blockIdx.x, tid = threadIdx.x;
    int* s = sums + t * 512 + tid * 2;
    const int v0 = s[0], v1 = s[1];
    const int tot = v0 + v1;
    __shared__ int part[256];
    part[tid] = tot;
    __syncthreads();
    for (int d = 1; d < 256; d <<= 1) {
        int v = (tid >= d) ? part[tid - d] : 0;
        __syncthreads();
        part[tid] += v;
        __syncthreads();
    }
    const int excl = part[tid] - tot;
    s[0] = excl; s[1] = excl + v0;
}

// ---- K2c: add chunk offsets -------------------------------------------------
__global__ void __launch_bounds__(256)
scan3(int* __restrict__ arr, const int* __restrict__ sums)
{
    const int t = blockIdx.y;
    const int add = sums[t * 512 + (blockIdx.x >> 2)];
    int4* p = (int4*)(arr + (long)t * CELLS + (long)blockIdx.x * 1024 + threadIdx.x * 4);
    int4 v = *p;
    v.x += add; v.y += add; v.z += add; v.w += add;
    *p = v;
}

// ---- K3: scatter particles into cell-sorted order (arr becomes END offsets) -
__global__ void __launch_bounds__(256)
scatter_cells(const float* __restrict__ xs, const float* __restrict__ def,
              int* __restrict__ arr,
              float4* __restrict__ sA, float2* __restrict__ sB, int N)
{
    const int p = blockIdx.x * blockDim.x + threadIdx.x;
    const int t = blockIdx.y;
    if (p >= N) return;
    const long i = (long)t * N + p;
    const float x = xs[i*3], y = xs[i*3+1], z = xs[i*3+2];
    float fx, fy, fz;
    int3 b = base_cell(x, y, z, fx, fy, fz);
    const int key = (b.x << 14) + (b.y << 7) + b.z;
    const int slot = atomicAdd(&arr[(long)t * CELLS + key], 1);
    const long o = (long)t * N + slot;
    sA[o] = make_float4(x, y, z, def[i*3]);
    sB[o] = make_float2(def[i*3+1], def[i*3+2]);
}

// ---- K4: merged-loop gather, one thread per cell, zero atomics --------------
__global__ void __launch_bounds__(256)
gather_cells2(const float4* __restrict__ sA, const float2* __restrict__ sB,
              const int* __restrict__ arr,
              float* __restrict__ grids, float* __restrict__ gdef, int N)
{
    const int cell = blockIdx.x * 256 + threadIdx.x;
    const int t = blockIdx.y;
    const int cz = cell & (G - 1);
    const int cy = (cell >> 7) & (G - 1);
    const int cx = cell >> 14;

    const int* a = arr + (long)t * CELLS;
    const long pbase = (long)t * N;
    const int zlo = max(cz - 2, 0);

    // 9 source rows: rx = cx-2+r/3, ry = cy-2+r%3 (fixed map; OOB rows empty).
    // Ranges over the cell-sorted order: [start(row+zlo), end(row+cz)].
    int s0_[9], cn_[9];
    #pragma unroll
    for (int r = 0; r < 9; ++r) {
        const int rx = cx - 2 + r / 3;          // compile-time r/3, r%3
        const int ry = cy - 2 + r % 3;
        int b = 0, e = 0;
        if (rx >= 0 && ry >= 0) {               // rx,ry>125 rows naturally empty
            const int row = (rx << 14) + (ry << 7);
            const int gs  = row + zlo;          // >= 0
            e = a[row + cz];                    // end(cell row+cz)
            b = gs ? a[gs - 1] : 0;             // start(cell row+zlo)
        }
        s0_[r] = b;
        cn_[r] = max(e - b, 0);
    }

    // exclusive prefix + per-segment adjust, all named registers
    const int p1 = cn_[0];
    const int p2 = p1 + cn_[1];
    const int p3 = p2 + cn_[2];
    const int p4 = p3 + cn_[3];
    const int p5 = p4 + cn_[4];
    const int p6 = p5 + cn_[5];
    const int p7 = p6 + cn_[6];
    const int p8 = p7 + cn_[7];
    const int tot = p8 + cn_[8];
    const int adj0 = s0_[0];
    const int adj1 = s0_[1] - p1;
    const int adj2 = s0_[2] - p2;
    const int adj3 = s0_[3] - p3;
    const int adj4 = s0_[4] - p4;
    const int adj5 = s0_[5] - p5;
    const int adj6 = s0_[6] - p6;
    const int adj7 = s0_[7] - p7;
    const int adj8 = s0_[8] - p8;

    float m = 0.f, v0 = 0.f, v1 = 0.f, v2 = 0.f;
    for (int j = 0; j < tot; ++j) {
        const int g1 = (j >= p1), g2 = (j >= p2), g3 = (j >= p3), g4 = (j >= p4),
                  g5 = (j >= p5), g6 = (j >= p6), g7 = (j >= p7), g8 = (j >= p8);
        int ad = adj0;
        ad = g1 ? adj1 : ad;  ad = g2 ? adj2 : ad;  ad = g3 ? adj3 : ad;
        ad = g4 ? adj4 : ad;  ad = g5 ? adj5 : ad;  ad = g6 ? adj6 : ad;
        ad = g7 ? adj7 : ad;  ad = g8 ? adj8 : ad;
        // dp = (dX<<2)|dY, dX = 2-r/3, dY = 2-r%3
        const int dp = 10 - g1 - g2 - 2*g3 - g4 - g5 - 2*g6 - g7 - g8;
        const int idx = j + ad;

        const float4 A = sA[pbase + idx];
        const float2 B = sB[pbase + idx];
        float fx, fy, fz;
        const int3 b = base_cell(A.x, A.y, A.z, fx, fy, fz);
        const float w = wsel(fx, dp >> 2) * wsel(fy, dp & 3) * wsel(fz, cz - b.z);
        m  += w;                                 // P_MASS = 1
        v0 += w * A.w;
        v1 += w * B.x;
        v2 += w * B.y;
    }

    const long gidx = (long)t * CELLS + cell;
    grids[gidx]      = m;
    gdef[gidx*3 + 0] = v0;
    gdef[gidx*3 + 1] = v1;
    gdef[gidx*3 + 2] = v2;
}

// ---- last-resort fallback: direct global atomics ----------------------------
__global__ void __launch_bounds__(256)
p2g_direct(const float* __restrict__ xs, const float* __restrict__ def,
           float* __restrict__ grids, float* __restrict__ gdef, int N)
{
    const int p = blockIdx.x * blockDim.x + threadIdx.x;
    const int t = blockIdx.y;
    if (p >= N) return;
    const long i = (long)t * N + p;
    const float dx = def[i*3], dy = def[i*3+1], dz = def[i*3+2];
    float fx, fy, fz;
    int3 b = base_cell(xs[i*3], xs[i*3+1], xs[i*3+2], fx, fy, fz);
    float wx[3], wy[3], wz[3];
    wx[0] = 0.5f*(1.5f-fx)*(1.5f-fx); wx[1] = 0.75f-(fx-1.f)*(fx-1.f); wx[2] = 0.5f*(fx-0.5f)*(fx-0.5f);
    wy[0] = 0.5f*(1.5f-fy)*(1.5f-fy); wy[1] = 0.75f-(fy-1.f)*(fy-1.f); wy[2] = 0.5f*(fy-0.5f)*(fy-0.5f);
    wz[0] = 0.5f*(1.5f-fz)*(1.5f-fz); wz[1] = 0.75f-(fz-1.f)*(fz-1.f); wz[2] = 0.5f*(fz-0.5f)*(fz-0.5f);
    const long tbase = (long)t * CELLS;
    #pragma unroll
    for (int ii = 0; ii < 3; ++ii) {
        const long xoff = tbase + (long)(b.x + ii) * (G * G);
        #pragma unroll
        for (int jj = 0; jj < 3; ++jj) {
            const float wij = wx[ii] * wy[jj];
            const long yoff = xoff + (long)(b.y + jj) * G;
            #pragma unroll
            for (int kk = 0; kk < 3; ++kk) {
                const float w = wij * wz[kk];
                const long idx = yoff + (b.z + kk);
                atomicAdd(&grids[idx], w);
                atomicAdd(&gdef[idx*3+0], w * dx);
                atomicAdd(&gdef[idx*3+1], w * dy);
                atomicAdd(&gdef[idx*3+2], w * dz);
            }
        }
    }
}

extern "C" void kernel_launch(void* const* d_in, const int* in_sizes, int n_in,
                              void* d_out, int out_size, void* d_ws, size_t ws_size,
                              hipStream_t stream)
{
    const float* xs  = (const float*)d_in[0];
    const float* def = (const float*)d_in[1];
    float* out = (float*)d_out;

    const int T = (int)(out_size / ((long)CELLS * 4));
    const int N = in_sizes[0] / (3 * T);

    float* grids = out;
    float* gdef  = out + (long)T * CELLS;

    const size_t szA    = (size_t)T * N * sizeof(float4);    // 12.8 MB
    const size_t szB    = (size_t)T * N * sizeof(float2);    //  6.4 MB
    const size_t szArr  = (size_t)T * CELLS * sizeof(int);   // 64 MB
    const size_t szSums = (size_t)T * 512 * sizeof(int);
    const size_t need   = szA + szB + szArr + szSums;

    if (ws_size >= need) {
        char* ws = (char*)d_ws;
        float4* sA   = (float4*)ws;  ws += szA;
        float2* sB   = (float2*)ws;  ws += szB;
        int*    arr  = (int*)ws;     ws += szArr;
        int*    sums = (int*)ws;

        hipMemsetAsync(arr, 0, szArr, stream);

        dim3 pgrid((N + 255) / 256, T);
        cell_hist    <<<pgrid, dim3(256), 0, stream>>>(xs, arr, N);
        scan1        <<<dim3(512, T), dim3(256), 0, stream>>>(arr, sums);
        scan2        <<<dim3(T), dim3(256), 0, stream>>>(sums);
        scan3        <<<dim3(CELLS / 1024, T), dim3(256), 0, stream>>>(arr, sums);
        scatter_cells<<<pgrid, dim3(256), 0, stream>>>(xs, def, arr, sA, sB, N);
        gather_cells2<<<dim3(CELLS / 256, T), dim3(256), 0, stream>>>(sA, sB, arr,
                                                                      grids, gdef, N);
        return;
    }

    hipMemsetAsync(d_out, 0, (size_t)out_size * sizeof(float), stream);
    dim3 grid((N + 255) / 256, T);
    p2g_direct<<<grid, dim3(256), 0, stream>>>(xs, def, grids, gdef, N);
}

// Round 12
// 319.364 us; speedup vs baseline: 1.9910x; 1.0849x over previous
//
#include <hip/hip_runtime.h>

// MPM P2G, quadratic B-spline, 3x3x3 stencil.
// Cell-sort + cooperative column-wave gather:
//   pre-pass: counting-sort by clamped base cell (z in low key bits);
//             scan3 folded away (chunk bases added at use sites).
//   gather:   one wave per 64-z half-column. Wave stages its <=~28 union
//             particles into LDS in ONE masked round (per-particle weights
//             computed ONCE), then a wave-UNIFORM loop accumulates:
//             1 broadcast b128 + 1 bank-spread ws read + ~8 VALU per particle.
//             No atomics, write-once coalesced stores.
// r11 bug: launched 4096 blocks instead of 8192 (waves = 16384 cols x 2
// halves / 4 per block) -> half the grid never written. Fixed grid only.
//
// Outputs (concatenated in d_out, fp32):
//   grids [T,G,G,G]   -> d_out[0 .. T*G^3)
//   gdef  [T,G,G,G,3] -> d_out[T*G^3 .. 4*T*G^3)

constexpr int   G      = 128;
constexpr int   CELLS  = G * G * G;       // 2,097,152
constexpr float MINN   = -15.0f;
constexpr float EXTENT = 40.0f;

__device__ __forceinline__ int3 base_cell(float x, float y, float z,
                                          float& fx, float& fy, float& fz)
{
    const float scale = (float)G / EXTENT;
    const float Xp = (x - MINN) * scale;
    const float Yp = (y - MINN) * scale;
    const float Zp = (z - MINN) * scale;
    int bx = (int)floorf(Xp - 0.5f);
    int by = (int)floorf(Yp - 0.5f);
    int bz = (int)floorf(Zp - 0.5f);
    // f from the UNclamped base (matches reference); clamp affects indices only
    fx = Xp - (float)bx; fy = Yp - (float)by; fz = Zp - (float)bz;
    bx = min(max(bx, 0), G - 3);
    by = min(max(by, 0), G - 3);
    bz = min(max(bz, 0), G - 3);
    return make_int3(bx, by, bz);
}

__device__ __forceinline__ float wsel(float f, int d)
{
    const float r0 = 1.5f - f, r1 = f - 1.0f, r2 = f - 0.5f;
    const float w0 = 0.5f * r0 * r0;
    const float w1 = 0.75f - r1 * r1;
    const float w2 = 0.5f * r2 * r2;
    return d == 0 ? w0 : (d == 1 ? w1 : w2);
}

// ---- K1: per-cell histogram -------------------------------------------------
__global__ void __launch_bounds__(256)
cell_hist(const float* __restrict__ xs, int* __restrict__ arr, int N)
{
    const int p = blockIdx.x * blockDim.x + threadIdx.x;
    const int t = blockIdx.y;
    if (p >= N) return;
    const long i = (long)t * N + p;
    float fx, fy, fz;
    int3 b = base_cell(xs[i*3], xs[i*3+1], xs[i*3+2], fx, fy, fz);
    const int key = (b.x << 14) + (b.y << 7) + b.z;
    atomicAdd(&arr[(long)t * CELLS + key], 1);
}

// ---- K2a: per-4096-chunk exclusive scan (in place) + chunk totals -----------
__global__ void __launch_bounds__(256)
scan1(int* __restrict__ arr, int* __restrict__ sums)
{
    const int t = blockIdx.y, tid = threadIdx.x;
    int* a = arr + (long)t * CELLS + (long)blockIdx.x * 4096 + tid * 16;
    int local[16], s = 0;
    #pragma unroll
    for (int i = 0; i < 16; ++i) { const int v = a[i]; local[i] = s; s += v; }
    __shared__ int part[256];
    part[tid] = s;
    __syncthreads();
    const int own = s;
    for (int d = 1; d < 256; d <<= 1) {
        int v = (tid >= d) ? part[tid - d] : 0;
        __syncthreads();
        part[tid] += v;
        __syncthreads();
    }
    const int excl = part[tid] - own;
    #pragma unroll
    for (int i = 0; i < 16; ++i) a[i] = excl + local[i];
    if (tid == 255) sums[t * 512 + blockIdx.x] = part[255];
}

// ---- K2b: exclusive scan of the 512 chunk totals per timestep ---------------
__global__ void __launch_bounds__(256)
scan2(int* __restrict__ sums)
{
    const int t = blockIdx.x, tid = threadIdx.x;
    int* s = sums + t * 512 + tid * 2;
    const int v0 = s[0], v1 = s[1];
    const int tot = v0 + v1;
    __shared__ int part[256];
    part[tid] = tot;
    __syncthreads();
    for (int d = 1; d < 256; d <<= 1) {
        int v = (tid >= d) ? part[tid - d] : 0;
        __syncthreads();
        part[tid] += v;
        __syncthreads();
    }
    const int excl = part[tid] - tot;
    s[0] = excl; s[1] = excl + v0;
}

// ---- K3: scatter into cell-sorted order; payload = {fx,fy,Zp,d0|d1,d2} ------
__global__ void __launch_bounds__(256)
scatter_cells(const float* __restrict__ xs, const float* __restrict__ def,
              int* __restrict__ arr, const int* __restrict__ sums,
              float4* __restrict__ sA, float2* __restrict__ sB, int N)
{
    const int p = blockIdx.x * blockDim.x + threadIdx.x;
    const int t = blockIdx.y;
    if (p >= N) return;
    const long i = (long)t * N + p;
    const float x = xs[i*3], y = xs[i*3+1], z = xs[i*3+2];
    float fx, fy, fz;
    int3 b = base_cell(x, y, z, fx, fy, fz);
    const float Zp = (z - MINN) * ((float)G / EXTENT);
    const int key = (b.x << 14) + (b.y << 7) + b.z;
    const int slot = atomicAdd(&arr[(long)t * CELLS + key], 1)
                   + sums[t * 512 + (key >> 12)];
    const long o = (long)t * N + slot;
    sA[o] = make_float4(fx, fy, Zp, def[i*3]);
    sB[o] = make_float2(def[i*3+1], def[i*3+2]);
}

// ---- K4: cooperative column-wave gather -------------------------------------
__global__ void __launch_bounds__(256)
gather_cells3(const float4* __restrict__ sA, const float2* __restrict__ sB,
              const int* __restrict__ arr, const int* __restrict__ sums,
              float* __restrict__ grids, float* __restrict__ gdef, int N)
{
    const int wid  = threadIdx.x >> 6;
    const int lane = threadIdx.x & 63;
    const int t = blockIdx.y;
    const int W = blockIdx.x * 4 + wid;          // wave id: 2 halves per column
    const int col = W >> 1;                      // (cx,cy) column
    const int zbase = (W & 1) << 6;              // 0 or 64
    const int cy = col & (G - 1);
    const int cx = col >> 7;
    const int cz = zbase + lane;                 // this lane's output cell z

    __shared__ float recS[4][256];               // per-wave: 64 x {bz,d0,d1,d2}
    __shared__ float wsS[4][3 * 65];             // per-wave: ws[k][p], 65-stride

    const int* a  = arr + (long)t * CELLS;
    const int* sm = sums + t * 512;
    const long pbase = (long)t * N;

    // --- 9 source-row descriptors in lanes 0..8 ------------------------------
    const int rdiv = (lane >= 3) + (lane >= 6);
    const int rmod = lane - 3 * rdiv;
    const int rx = cx - 2 + rdiv;
    const int ry = cy - 2 + rmod;
    int beg = 0, end = 0;
    if (lane < 9 && rx >= 0 && ry >= 0) {
        const int row = (rx << 14) + (ry << 7);
        const int c1 = row + zbase + 63;         // end(last z in window)
        end = a[c1] + sm[c1 >> 12];
        const int c0 = row + max(zbase - 2, 0) - 1;
        beg = (c0 >= 0) ? (a[c0] + sm[c0 >> 12]) : 0;
    }
    const int cnt = max(end - beg, 0);
    int incl = cnt;
    #pragma unroll
    for (int d = 1; d <= 8; d <<= 1) {
        int v = __shfl_up(incl, d);
        if (lane >= d) incl += v;
    }
    const int excl = incl - cnt;
    const int tot  = __shfl(incl, 8);
    const int p1 = __shfl(excl, 1), p2 = __shfl(excl, 2), p3 = __shfl(excl, 3),
              p4 = __shfl(excl, 4), p5 = __shfl(excl, 5), p6 = __shfl(excl, 6),
              p7 = __shfl(excl, 7), p8 = __shfl(excl, 8);
    const int adj  = beg - excl;
    const int adj0 = __shfl(adj, 0), adj1 = __shfl(adj, 1), adj2 = __shfl(adj, 2),
              adj3 = __shfl(adj, 3), adj4 = __shfl(adj, 4), adj5 = __shfl(adj, 5),
              adj6 = __shfl(adj, 6), adj7 = __shfl(adj, 7), adj8 = __shfl(adj, 8);

    float* rec = recS[wid];
    float* ws  = wsS[wid];
    float m = 0.f, v0 = 0.f, v1 = 0.f, v2 = 0.f;

    for (int p0 = 0; p0 < tot; p0 += 64) {
        // ---- stage: one masked round, per-particle weights computed once ----
        const int j = p0 + lane;
        if (j < tot) {
            const int g1 = (j >= p1), g2 = (j >= p2), g3 = (j >= p3), g4 = (j >= p4),
                      g5 = (j >= p5), g6 = (j >= p6), g7 = (j >= p7), g8 = (j >= p8);
            int ad = adj0;
            ad = g1 ? adj1 : ad;  ad = g2 ? adj2 : ad;  ad = g3 ? adj3 : ad;
            ad = g4 ? adj4 : ad;  ad = g5 ? adj5 : ad;  ad = g6 ? adj6 : ad;
            ad = g7 ? adj7 : ad;  ad = g8 ? adj8 : ad;
            const int dp = 10 - g1 - g2 - 2*g3 - g4 - g5 - 2*g6 - g7 - g8;
            const int idx = j + ad;

            const float4 A = sA[pbase + idx];    // {fx, fy, Zp, d0}
            const float2 B = sB[pbase + idx];    // {d1, d2}
            const float bzf = floorf(A.z - 0.5f);
            const float fz  = A.z - bzf;
            const float wxy = wsel(A.x, dp >> 2) * wsel(A.y, dp & 3);
            const float q0 = 1.5f - fz, q1 = fz - 1.0f, q2 = fz - 0.5f;
            ((float4*)rec)[lane] =
                make_float4(__int_as_float((int)bzf), A.w, B.x, B.y);
            ws[lane]       = wxy * (0.5f * q0 * q0);
            ws[65 + lane]  = wxy * (0.75f - q1 * q1);
            ws[130 + lane] = wxy * (0.5f * q2 * q2);
        }
        // ---- accumulate: wave-uniform loop over staged particles ------------
        const int cc = min(tot - p0, 64);
        for (int p = 0; p < cc; ++p) {
            const float4 R = ((const float4*)rec)[p];   // broadcast b128
            const int bz = __float_as_int(R.x);
            const int k  = cz - bz;
            const int ka = min(max(k, 0), 2);
            const float wsv = ws[ka * 65 + p];          // 3 banks, no conflict
            const float w = ((unsigned)k <= 2u) ? wsv : 0.0f;
            m  += w;                                    // P_MASS = 1
            v0 += w * R.y;
            v1 += w * R.z;
            v2 += w * R.w;
        }
    }

    // flush: lane owns cell (t, cx, cy, cz) -> write-once coalesced stores
    const long gidx = (long)t * CELLS + ((long)col << 7) + cz;
    grids[gidx]      = m;
    gdef[gidx*3 + 0] = v0;
    gdef[gidx*3 + 1] = v1;
    gdef[gidx*3 + 2] = v2;
}

// ---- last-resort fallback: direct global atomics ----------------------------
__global__ void __launch_bounds__(256)
p2g_direct(const float* __restrict__ xs, const float* __restrict__ def,
           float* __restrict__ grids, float* __restrict__ gdef, int N)
{
    const int p = blockIdx.x * blockDim.x + threadIdx.x;
    const int t = blockIdx.y;
    if (p >= N) return;
    const long i = (long)t * N + p;
    const float dx = def[i*3], dy = def[i*3+1], dz = def[i*3+2];
    float fx, fy, fz;
    int3 b = base_cell(xs[i*3], xs[i*3+1], xs[i*3+2], fx, fy, fz);
    float wx[3], wy[3], wz[3];
    wx[0] = 0.5f*(1.5f-fx)*(1.5f-fx); wx[1] = 0.75f-(fx-1.f)*(fx-1.f); wx[2] = 0.5f*(fx-0.5f)*(fx-0.5f);
    wy[0] = 0.5f*(1.5f-fy)*(1.5f-fy); wy[1] = 0.75f-(fy-1.f)*(fy-1.f); wy[2] = 0.5f*(fy-0.5f)*(fy-0.5f);
    wz[0] = 0.5f*(1.5f-fz)*(1.5f-fz); wz[1] = 0.75f-(fz-1.f)*(fz-1.f); wz[2] = 0.5f*(fz-0.5f)*(fz-0.5f);
    const long tbase = (long)t * CELLS;
    #pragma unroll
    for (int ii = 0; ii < 3; ++ii) {
        const long xoff = tbase + (long)(b.x + ii) * (G * G);
        #pragma unroll
        for (int jj = 0; jj < 3; ++jj) {
            const float wij = wx[ii] * wy[jj];
            const long yoff = xoff + (long)(b.y + jj) * G;
            #pragma unroll
            for (int kk = 0; kk < 3; ++kk) {
                const float w = wij * wz[kk];
                const long idx = yoff + (b.z + kk);
                atomicAdd(&grids[idx], w);
                atomicAdd(&gdef[idx*3+0], w * dx);
                atomicAdd(&gdef[idx*3+1], w * dy);
                atomicAdd(&gdef[idx*3+2], w * dz);
            }
        }
    }
}

extern "C" void kernel_launch(void* const* d_in, const int* in_sizes, int n_in,
                              void* d_out, int out_size, void* d_ws, size_t ws_size,
                              hipStream_t stream)
{
    const float* xs  = (const float*)d_in[0];
    const float* def = (const float*)d_in[1];
    float* out = (float*)d_out;

    const int T = (int)(out_size / ((long)CELLS * 4));
    const int N = in_sizes[0] / (3 * T);

    float* grids = out;
    float* gdef  = out + (long)T * CELLS;

    const size_t szA    = (size_t)T * N * sizeof(float4);    // 12.8 MB
    const size_t szB    = (size_t)T * N * sizeof(float2);    //  6.4 MB
    const size_t szArr  = (size_t)T * CELLS * sizeof(int);   // 64 MB
    const size_t szSums = (size_t)T * 512 * sizeof(int);
    const size_t need   = szA + szB + szArr + szSums;

    if (ws_size >= need) {
        char* ws = (char*)d_ws;
        float4* sA   = (float4*)ws;  ws += szA;
        float2* sB   = (float2*)ws;  ws += szB;
        int*    arr  = (int*)ws;     ws += szArr;
        int*    sums = (int*)ws;

        hipMemsetAsync(arr, 0, szArr, stream);

        dim3 pgrid((N + 255) / 256, T);
        cell_hist    <<<pgrid, dim3(256), 0, stream>>>(xs, arr, N);
        scan1        <<<dim3(512, T), dim3(256), 0, stream>>>(arr, sums);
        scan2        <<<dim3(T), dim3(256), 0, stream>>>(sums);
        scatter_cells<<<pgrid, dim3(256), 0, stream>>>(xs, def, arr, sums, sA, sB, N);
        // waves = (G*G columns) x 2 halves = 32768; 4 waves/block -> 8192 blocks
        gather_cells3<<<dim3(CELLS / 256, T), dim3(256), 0, stream>>>(
            sA, sB, arr, sums, grids, gdef, N);
        return;
    }

    hipMemsetAsync(d_out, 0, (size_t)out_size * sizeof(float), stream);
    dim3 grid((N + 255) / 256, T);
    p2g_direct<<<grid, dim3(256), 0, stream>>>(xs, def, grids, gdef, N);
}

// Round 13
// 285.337 us; speedup vs baseline: 2.2284x; 1.1193x over previous
//
#include <hip/hip_runtime.h>

// MPM P2G, quadratic B-spline, 3x3x3 stencil.
// Cell-sort + cooperative gather, v4: wave = 4 groups x 16 z-cells.
// Each group stages <=16 of its ~8 particles per round (weights computed
// once), accumulate loop runs max-over-4-groups (~11) trips with 4 particles
// served per iteration -> ~2.5x fewer masked-lane iterations than v3 (r12).
// No atomics in gather, write-once coalesced stores.
//
// Outputs (concatenated in d_out, fp32):
//   grids [T,G,G,G]   -> d_out[0 .. T*G^3)
//   gdef  [T,G,G,G,3] -> d_out[T*G^3 .. 4*T*G^3)

constexpr int   G      = 128;
constexpr int   CELLS  = G * G * G;       // 2,097,152
constexpr float MINN   = -15.0f;
constexpr float EXTENT = 40.0f;

__device__ __forceinline__ int3 base_cell(float x, float y, float z,
                                          float& fx, float& fy, float& fz)
{
    const float scale = (float)G / EXTENT;
    const float Xp = (x - MINN) * scale;
    const float Yp = (y - MINN) * scale;
    const float Zp = (z - MINN) * scale;
    int bx = (int)floorf(Xp - 0.5f);
    int by = (int)floorf(Yp - 0.5f);
    int bz = (int)floorf(Zp - 0.5f);
    // f from the UNclamped base (matches reference); clamp affects indices only
    fx = Xp - (float)bx; fy = Yp - (float)by; fz = Zp - (float)bz;
    bx = min(max(bx, 0), G - 3);
    by = min(max(by, 0), G - 3);
    bz = min(max(bz, 0), G - 3);
    return make_int3(bx, by, bz);
}

__device__ __forceinline__ float wsel(float f, int d)
{
    const float r0 = 1.5f - f, r1 = f - 1.0f, r2 = f - 0.5f;
    const float w0 = 0.5f * r0 * r0;
    const float w1 = 0.75f - r1 * r1;
    const float w2 = 0.5f * r2 * r2;
    return d == 0 ? w0 : (d == 1 ? w1 : w2);
}

// ---- K1: per-cell histogram -------------------------------------------------
__global__ void __launch_bounds__(256)
cell_hist(const float* __restrict__ xs, int* __restrict__ arr, int N)
{
    const int p = blockIdx.x * blockDim.x + threadIdx.x;
    const int t = blockIdx.y;
    if (p >= N) return;
    const long i = (long)t * N + p;
    float fx, fy, fz;
    int3 b = base_cell(xs[i*3], xs[i*3+1], xs[i*3+2], fx, fy, fz);
    const int key = (b.x << 14) + (b.y << 7) + b.z;
    atomicAdd(&arr[(long)t * CELLS + key], 1);
}

// ---- K2a: per-4096-chunk exclusive scan (in place) + chunk totals -----------
__global__ void __launch_bounds__(256)
scan1(int* __restrict__ arr, int* __restrict__ sums)
{
    const int t = blockIdx.y, tid = threadIdx.x;
    int* a = arr + (long)t * CELLS + (long)blockIdx.x * 4096 + tid * 16;
    int local[16], s = 0;
    #pragma unroll
    for (int i = 0; i < 16; ++i) { const int v = a[i]; local[i] = s; s += v; }
    __shared__ int part[256];
    part[tid] = s;
    __syncthreads();
    const int own = s;
    for (int d = 1; d < 256; d <<= 1) {
        int v = (tid >= d) ? part[tid - d] : 0;
        __syncthreads();
        part[tid] += v;
        __syncthreads();
    }
    const int excl = part[tid] - own;
    #pragma unroll
    for (int i = 0; i < 16; ++i) a[i] = excl + local[i];
    if (tid == 255) sums[t * 512 + blockIdx.x] = part[255];
}

// ---- K2b: exclusive scan of the 512 chunk totals per timestep ---------------
__global__ void __launch_bounds__(256)
scan2(int* __restrict__ sums)
{
    const int t = blockIdx.x, tid = threadIdx.x;
    int* s = sums + t * 512 + tid * 2;
    const int v0 = s[0], v1 = s[1];
    const int tot = v0 + v1;
    __shared__ int part[256];
    part[tid] = tot;
    __syncthreads();
    for (int d = 1; d < 256; d <<= 1) {
        int v = (tid >= d) ? part[tid - d] : 0;
        __syncthreads();
        part[tid] += v;
        __syncthreads();
    }
    const int excl = part[tid] - tot;
    s[0] = excl; s[1] = excl + v0;
}

// ---- K3: scatter into cell-sorted order; payload = {fx,fy,Zp,d0|d1,d2} ------
__global__ void __launch_bounds__(256)
scatter_cells(const float* __restrict__ xs, const float* __restrict__ def,
              int* __restrict__ arr, const int* __restrict__ sums,
              float4* __restrict__ sA, float2* __restrict__ sB, int N)
{
    const int p = blockIdx.x * blockDim.x + threadIdx.x;
    const int t = blockIdx.y;
    if (p >= N) return;
    const long i = (long)t * N + p;
    const float x = xs[i*3], y = xs[i*3+1], z = xs[i*3+2];
    float fx, fy, fz;
    int3 b = base_cell(x, y, z, fx, fy, fz);
    const float Zp = (z - MINN) * ((float)G / EXTENT);
    const int key = (b.x << 14) + (b.y << 7) + b.z;
    const int slot = atomicAdd(&arr[(long)t * CELLS + key], 1)
                   + sums[t * 512 + (key >> 12)];
    const long o = (long)t * N + slot;
    sA[o] = make_float4(fx, fy, Zp, def[i*3]);
    sB[o] = make_float2(def[i*3+1], def[i*3+2]);
}

// ---- K4 v4: 4 groups x 16 z per wave ----------------------------------------
__global__ void __launch_bounds__(256)
gather_cells4(const float4* __restrict__ sA, const float2* __restrict__ sB,
              const int* __restrict__ arr, const int* __restrict__ sums,
              float* __restrict__ grids, float* __restrict__ gdef, int N)
{
    const int wid  = threadIdx.x >> 6;
    const int lane = threadIdx.x & 63;
    const int g    = lane >> 4;                  // group 0..3
    const int zl   = lane & 15;                  // z within group
    const int t = blockIdx.y;
    const int W = blockIdx.x * 4 + wid;
    const int col = W >> 1;                      // (cx,cy) column
    const int zbase = (W & 1) << 6;              // 0 or 64
    const int cy = col & (G - 1);
    const int cx = col >> 7;
    const int cz = zbase + lane;                 // lane's output z (g*16+zl)

    __shared__ int   descB[4][4][9];             // [wid][g][r] segment begin
    __shared__ int   descC[4][4][9];             // [wid][g][r] segment count
    __shared__ float4 rec[4][4][17];             // [wid][g][slot] {bz,d0,d1,d2}
    __shared__ float  ws[4][3][4][17];           // [wid][k][g][slot]

    const int* a  = arr + (long)t * CELLS;
    const int* sm = sums + t * 512;
    const long pbase = (long)t * N;

    // --- 36 segment descriptors (4 groups x 9 rows), lanes 0..35 -------------
    if (lane < 36) {
        const int g2 = lane / 9;                 // magic-mul
        const int r2 = lane - 9 * g2;
        const int rx = cx - 2 + r2 / 3;
        const int ry = cy - 2 + r2 % 3;
        int beg = 0, cnt = 0;
        if (rx >= 0 && ry >= 0) {
            const int row = (rx << 14) + (ry << 7);
            const int Z0  = zbase + (g2 << 4);
            const int c1  = row + Z0 + 15;       // end(last z in group window)
            const int e   = a[c1] + sm[c1 >> 12];
            const int c0  = row + Z0 - 3;        // cell before window start
            beg = (c0 >= 0) ? (a[c0] + sm[c0 >> 12]) : 0;
            cnt = max(e - beg, 0);
        }
        descB[wid][g2][r2] = beg;
        descC[wid][g2][r2] = cnt;
    }

    // --- per-group prefix over 9 segments (width-16 shfl) --------------------
    int beg = 0, cnt = 0;
    if (zl < 9) { beg = descB[wid][g][zl]; cnt = descC[wid][g][zl]; }
    int incl = cnt;
    #pragma unroll
    for (int d = 1; d <= 8; d <<= 1) {
        int v = __shfl_up(incl, d, 16);
        if (zl >= d) incl += v;
    }
    const int excl = incl - cnt;
    const int tot  = __shfl(incl, 8, 16);        // group total
    const int p1 = __shfl(excl, 1, 16), p2 = __shfl(excl, 2, 16),
              p3 = __shfl(excl, 3, 16), p4 = __shfl(excl, 4, 16),
              p5 = __shfl(excl, 5, 16), p6 = __shfl(excl, 6, 16),
              p7 = __shfl(excl, 7, 16), p8 = __shfl(excl, 8, 16);
    const int adj  = beg - excl;
    const int adj0 = __shfl(adj, 0, 16), adj1 = __shfl(adj, 1, 16),
              adj2 = __shfl(adj, 2, 16), adj3 = __shfl(adj, 3, 16),
              adj4 = __shfl(adj, 4, 16), adj5 = __shfl(adj, 5, 16),
              adj6 = __shfl(adj, 6, 16), adj7 = __shfl(adj, 7, 16),
              adj8 = __shfl(adj, 8, 16);

    // wave-max of the 4 group totals
    int mt = max(tot, __shfl_xor(tot, 16));
    mt = max(mt, __shfl_xor(mt, 32));

    float m = 0.f, v0 = 0.f, v1 = 0.f, v2 = 0.f;

    for (int p0 = 0; p0 < mt; p0 += 16) {
        // ---- stage: each group fills up to 16 slots, weights computed once --
        const int j = p0 + zl;
        if (j < tot) {
            const int g1_ = (j >= p1), g2_ = (j >= p2), g3_ = (j >= p3),
                      g4_ = (j >= p4), g5_ = (j >= p5), g6_ = (j >= p6),
                      g7_ = (j >= p7), g8_ = (j >= p8);
            int ad = adj0;
            ad = g1_ ? adj1 : ad;  ad = g2_ ? adj2 : ad;  ad = g3_ ? adj3 : ad;
            ad = g4_ ? adj4 : ad;  ad = g5_ ? adj5 : ad;  ad = g6_ ? adj6 : ad;
            ad = g7_ ? adj7 : ad;  ad = g8_ ? adj8 : ad;
            const int dp = 10 - g1_ - g2_ - 2*g3_ - g4_ - g5_ - 2*g6_ - g7_ - g8_;
            const int idx = j + ad;

            const float4 A = sA[pbase + idx];    // {fx, fy, Zp, d0}
            const float2 B = sB[pbase + idx];    // {d1, d2}
            const float bzf = floorf(A.z - 0.5f);
            const float fz  = A.z - bzf;
            const float wxy = wsel(A.x, dp >> 2) * wsel(A.y, dp & 3);
            const float q0 = 1.5f - fz, q1 = fz - 1.0f, q2 = fz - 0.5f;
            rec[wid][g][zl] =
                make_float4(__int_as_float((int)bzf), A.w, B.x, B.y);
            ws[wid][0][g][zl] = wxy * (0.5f * q0 * q0);
            ws[wid][1][g][zl] = wxy * (0.75f - q1 * q1);
            ws[wid][2][g][zl] = wxy * (0.5f * q2 * q2);
        }
        // ---- accumulate this batch (group-uniform bound) --------------------
        const int cc = min(tot - p0, 16);
        for (int p = 0; p < cc; ++p) {
            const float4 R = rec[wid][g][p];     // 4 distinct banks, no conflict
            const int bz = __float_as_int(R.x);
            const int k  = cz - bz;
            const int ka = min(max(k, 0), 2);
            const float wsv = ws[wid][ka][g][p]; // 12 distinct banks (17-stride)
            const float w = ((unsigned)k <= 2u) ? wsv : 0.0f;
            m  += w;                             // P_MASS = 1
            v0 += w * R.y;
            v1 += w * R.z;
            v2 += w * R.w;
        }
    }

    // flush: lane owns cell (t, cx, cy, cz) -> write-once coalesced stores
    const long gidx = (long)t * CELLS + ((long)col << 7) + cz;
    grids[gidx]      = m;
    gdef[gidx*3 + 0] = v0;
    gdef[gidx*3 + 1] = v1;
    gdef[gidx*3 + 2] = v2;
}

// ---- last-resort fallback: direct global atomics ----------------------------
__global__ void __launch_bounds__(256)
p2g_direct(const float* __restrict__ xs, const float* __restrict__ def,
           float* __restrict__ grids, float* __restrict__ gdef, int N)
{
    const int p = blockIdx.x * blockDim.x + threadIdx.x;
    const int t = blockIdx.y;
    if (p >= N) return;
    const long i = (long)t * N + p;
    const float dx = def[i*3], dy = def[i*3+1], dz = def[i*3+2];
    float fx, fy, fz;
    int3 b = base_cell(xs[i*3], xs[i*3+1], xs[i*3+2], fx, fy, fz);
    float wx[3], wy[3], wz[3];
    wx[0] = 0.5f*(1.5f-fx)*(1.5f-fx); wx[1] = 0.75f-(fx-1.f)*(fx-1.f); wx[2] = 0.5f*(fx-0.5f)*(fx-0.5f);
    wy[0] = 0.5f*(1.5f-fy)*(1.5f-fy); wy[1] = 0.75f-(fy-1.f)*(fy-1.f); wy[2] = 0.5f*(fy-0.5f)*(fy-0.5f);
    wz[0] = 0.5f*(1.5f-fz)*(1.5f-fz); wz[1] = 0.75f-(fz-1.f)*(fz-1.f); wz[2] = 0.5f*(fz-0.5f)*(fz-0.5f);
    const long tbase = (long)t * CELLS;
    #pragma unroll
    for (int ii = 0; ii < 3; ++ii) {
        const long xoff = tbase + (long)(b.x + ii) * (G * G);
        #pragma unroll
        for (int jj = 0; jj < 3; ++jj) {
            const float wij = wx[ii] * wy[jj];
            const long yoff = xoff + (long)(b.y + jj) * G;
            #pragma unroll
            for (int kk = 0; kk < 3; ++kk) {
                const float w = wij * wz[kk];
                const long idx = yoff + (b.z + kk);
                atomicAdd(&grids[idx], w);
                atomicAdd(&gdef[idx*3+0], w * dx);
                atomicAdd(&gdef[idx*3+1], w * dy);
                atomicAdd(&gdef[idx*3+2], w * dz);
            }
        }
    }
}

extern "C" void kernel_launch(void* const* d_in, const int* in_sizes, int n_in,
                              void* d_out, int out_size, void* d_ws, size_t ws_size,
                              hipStream_t stream)
{
    const float* xs  = (const float*)d_in[0];
    const float* def = (const float*)d_in[1];
    float* out = (float*)d_out;

    const int T = (int)(out_size / ((long)CELLS * 4));
    const int N = in_sizes[0] / (3 * T);

    float* grids = out;
    float* gdef  = out + (long)T * CELLS;

    const size_t szA    = (size_t)T * N * sizeof(float4);    // 12.8 MB
    const size_t szB    = (size_t)T * N * sizeof(float2);    //  6.4 MB
    const size_t szArr  = (size_t)T * CELLS * sizeof(int);   // 64 MB
    const size_t szSums = (size_t)T * 512 * sizeof(int);
    const size_t need   = szA + szB + szArr + szSums;

    if (ws_size >= need) {
        char* ws = (char*)d_ws;
        float4* sA   = (float4*)ws;  ws += szA;
        float2* sB   = (float2*)ws;  ws += szB;
        int*    arr  = (int*)ws;     ws += szArr;
        int*    sums = (int*)ws;

        hipMemsetAsync(arr, 0, szArr, stream);

        dim3 pgrid((N + 255) / 256, T);
        cell_hist    <<<pgrid, dim3(256), 0, stream>>>(xs, arr, N);
        scan1        <<<dim3(512, T), dim3(256), 0, stream>>>(arr, sums);
        scan2        <<<dim3(T), dim3(256), 0, stream>>>(sums);
        scatter_cells<<<pgrid, dim3(256), 0, stream>>>(xs, def, arr, sums, sA, sB, N);
        // waves = 16384 cols x 2 halves = 32768; 4 waves/block -> 8192 blocks
        gather_cells4<<<dim3(CELLS / 256, T), dim3(256), 0, stream>>>(
            sA, sB, arr, sums, grids, gdef, N);
        return;
    }

    hipMemsetAsync(d_out, 0, (size_t)out_size * sizeof(float), stream);
    dim3 grid((N + 255) / 256, T);
    p2g_direct<<<grid, dim3(256), 0, stream>>>(xs, def, grids, gdef, N);
}

// Round 14
// 258.295 us; speedup vs baseline: 2.4617x; 1.1047x over previous
//
#include <hip/hip_runtime.h>

// MPM P2G, quadratic B-spline, 3x3x3 stencil.
// Bucket-4 sort + cooperative gather (v5):
//   pre-pass: counting-sort by 4-z-cell BUCKET (key = cell>>2) -> arr is
//             16 MB (L2-resident) instead of 64 MB; hist/scan/scatter all 4x
//             lighter. Within-bucket z-disorder is fine: gather k-filters.
//   gather:   v4 structure (wave = 4 groups x 16 z, staged LDS, weights
//             computed once); descriptors now in bucket space with 1-bucket
//             slop absorbed by the existing (unsigned)k<=2 filter.
// No atomics in gather, write-once coalesced stores.
//
// Outputs (concatenated in d_out, fp32):
//   grids [T,G,G,G]   -> d_out[0 .. T*G^3)
//   gdef  [T,G,G,G,3] -> d_out[T*G^3 .. 4*T*G^3)

constexpr int   G       = 128;
constexpr int   CELLS   = G * G * G;      // 2,097,152
constexpr int   BUCKETS = CELLS / 4;      // 524,288 per timestep (4 z-cells each)
constexpr float MINN    = -15.0f;
constexpr float EXTENT  = 40.0f;

__device__ __forceinline__ int3 base_cell(float x, float y, float z,
                                          float& fx, float& fy, float& fz)
{
    const float scale = (float)G / EXTENT;
    const float Xp = (x - MINN) * scale;
    const float Yp = (y - MINN) * scale;
    const float Zp = (z - MINN) * scale;
    int bx = (int)floorf(Xp - 0.5f);
    int by = (int)floorf(Yp - 0.5f);
    int bz = (int)floorf(Zp - 0.5f);
    // f from the UNclamped base (matches reference); clamp affects indices only
    fx = Xp - (float)bx; fy = Yp - (float)by; fz = Zp - (float)bz;
    bx = min(max(bx, 0), G - 3);
    by = min(max(by, 0), G - 3);
    bz = min(max(bz, 0), G - 3);
    return make_int3(bx, by, bz);
}

__device__ __forceinline__ float wsel(float f, int d)
{
    const float r0 = 1.5f - f, r1 = f - 1.0f, r2 = f - 0.5f;
    const float w0 = 0.5f * r0 * r0;
    const float w1 = 0.75f - r1 * r1;
    const float w2 = 0.5f * r2 * r2;
    return d == 0 ? w0 : (d == 1 ? w1 : w2);
}

// ---- K1: per-bucket histogram -----------------------------------------------
__global__ void __launch_bounds__(256)
cell_hist(const float* __restrict__ xs, int* __restrict__ arr, int N)
{
    const int p = blockIdx.x * blockDim.x + threadIdx.x;
    const int t = blockIdx.y;
    if (p >= N) return;
    const long i = (long)t * N + p;
    float fx, fy, fz;
    int3 b = base_cell(xs[i*3], xs[i*3+1], xs[i*3+2], fx, fy, fz);
    const int bucket = (b.x << 12) + (b.y << 5) + (b.z >> 2);
    atomicAdd(&arr[(long)t * BUCKETS + bucket], 1);
}

// ---- K2a: per-4096-chunk exclusive scan (in place) + chunk totals -----------
__global__ void __launch_bounds__(256)
scan1(int* __restrict__ arr, int* __restrict__ sums)
{
    const int t = blockIdx.y, tid = threadIdx.x;
    int* a = arr + (long)t * BUCKETS + (long)blockIdx.x * 4096 + tid * 16;
    int local[16], s = 0;
    #pragma unroll
    for (int i = 0; i < 16; ++i) { const int v = a[i]; local[i] = s; s += v; }
    __shared__ int part[256];
    part[tid] = s;
    __syncthreads();
    const int own = s;
    for (int d = 1; d < 256; d <<= 1) {
        int v = (tid >= d) ? part[tid - d] : 0;
        __syncthreads();
        part[tid] += v;
        __syncthreads();
    }
    const int excl = part[tid] - own;
    #pragma unroll
    for (int i = 0; i < 16; ++i) a[i] = excl + local[i];
    if (tid == 255) sums[t * 128 + blockIdx.x] = part[255];
}

// ---- K2b: exclusive scan of the 128 chunk totals per timestep ---------------
__global__ void __launch_bounds__(128)
scan2(int* __restrict__ sums)
{
    const int t = blockIdx.x, tid = threadIdx.x;   // 128 threads, 1 each
    const int v = sums[t * 128 + tid];
    __shared__ int part[128];
    part[tid] = v;
    __syncthreads();
    for (int d = 1; d < 128; d <<= 1) {
        int u = (tid >= d) ? part[tid - d] : 0;
        __syncthreads();
        part[tid] += u;
        __syncthreads();
    }
    sums[t * 128 + tid] = part[tid] - v;           // exclusive
}

// ---- K3: scatter into bucket-sorted order; payload = {fx,fy,Zp,d0|d1,d2} ----
__global__ void __launch_bounds__(256)
scatter_cells(const float* __restrict__ xs, const float* __restrict__ def,
              int* __restrict__ arr, const int* __restrict__ sums,
              float4* __restrict__ sA, float2* __restrict__ sB, int N)
{
    const int p = blockIdx.x * blockDim.x + threadIdx.x;
    const int t = blockIdx.y;
    if (p >= N) return;
    const long i = (long)t * N + p;
    const float x = xs[i*3], y = xs[i*3+1], z = xs[i*3+2];
    float fx, fy, fz;
    int3 b = base_cell(x, y, z, fx, fy, fz);
    const float Zp = (z - MINN) * ((float)G / EXTENT);
    const int bucket = (b.x << 12) + (b.y << 5) + (b.z >> 2);
    const int slot = atomicAdd(&arr[(long)t * BUCKETS + bucket], 1)
                   + sums[t * 128 + (bucket >> 12)];
    const long o = (long)t * N + slot;
    sA[o] = make_float4(fx, fy, Zp, def[i*3]);
    sB[o] = make_float2(def[i*3+1], def[i*3+2]);
}

// ---- K4 v5: 4 groups x 16 z per wave, bucket-space descriptors --------------
__global__ void __launch_bounds__(256)
gather_cells4(const float4* __restrict__ sA, const float2* __restrict__ sB,
              const int* __restrict__ arr, const int* __restrict__ sums,
              float* __restrict__ grids, float* __restrict__ gdef, int N)
{
    const int wid  = threadIdx.x >> 6;
    const int lane = threadIdx.x & 63;
    const int g    = lane >> 4;                  // group 0..3
    const int zl   = lane & 15;                  // z within group
    const int t = blockIdx.y;
    const int W = blockIdx.x * 4 + wid;
    const int col = W >> 1;                      // (cx,cy) column
    const int zbase = (W & 1) << 6;              // 0 or 64
    const int cy = col & (G - 1);
    const int cx = col >> 7;
    const int cz = zbase + lane;                 // lane's output z (g*16+zl)

    __shared__ int   descB[4][4][9];             // [wid][g][r] segment begin
    __shared__ int   descC[4][4][9];             // [wid][g][r] segment count
    __shared__ float4 rec[4][4][17];             // [wid][g][slot] {bz,d0,d1,d2}
    __shared__ float  ws[4][3][4][17];           // [wid][k][g][slot]

    const int* a  = arr + (long)t * BUCKETS;
    const int* sm = sums + t * 128;
    const long pbase = (long)t * N;

    // --- 36 segment descriptors (4 groups x 9 rows), lanes 0..35 -------------
    // group window z [Z0, Z0+15] needs bz in [Z0-2, Z0+15] -> buckets
    // [bb-1, bb+3] (bb = Z0>>2); range = [end(bb-2), end(bb+3)].
    // Over-coverage (bucket slop / previous-row tail) is k-filtered below.
    if (lane < 36) {
        const int g2 = lane / 9;                 // magic-mul
        const int r2 = lane - 9 * g2;
        const int rx = cx - 2 + r2 / 3;
        const int ry = cy - 2 + r2 % 3;
        int beg = 0, cnt = 0;
        if (rx >= 0 && ry >= 0) {
            const int rb = (rx << 12) + (ry << 5);
            const int bb = (zbase >> 2) + (g2 << 2);
            const int c1 = rb + bb + 3;          // end bucket of window
            const int e  = a[c1] + sm[c1 >> 12];
            const int c0 = rb + bb - 2;          // bucket before window start
            beg = (c0 >= 0) ? (a[c0] + sm[c0 >> 12]) : 0;
            cnt = max(e - beg, 0);
        }
        descB[wid][g2][r2] = beg;
        descC[wid][g2][r2] = cnt;
    }

    // --- per-group prefix over 9 segments (width-16 shfl) --------------------
    int beg = 0, cnt = 0;
    if (zl < 9) { beg = descB[wid][g][zl]; cnt = descC[wid][g][zl]; }
    int incl = cnt;
    #pragma unroll
    for (int d = 1; d <= 8; d <<= 1) {
        int v = __shfl_up(incl, d, 16);
        if (zl >= d) incl += v;
    }
    const int excl = incl - cnt;
    const int tot  = __shfl(incl, 8, 16);        // group total
    const int p1 = __shfl(excl, 1, 16), p2 = __shfl(excl, 2, 16),
              p3 = __shfl(excl, 3, 16), p4 = __shfl(excl, 4, 16),
              p5 = __shfl(excl, 5, 16), p6 = __shfl(excl, 6, 16),
              p7 = __shfl(excl, 7, 16), p8 = __shfl(excl, 8, 16);
    const int adj  = beg - excl;
    const int adj0 = __shfl(adj, 0, 16), adj1 = __shfl(adj, 1, 16),
              adj2 = __shfl(adj, 2, 16), adj3 = __shfl(adj, 3, 16),
              adj4 = __shfl(adj, 4, 16), adj5 = __shfl(adj, 5, 16),
              adj6 = __shfl(adj, 6, 16), adj7 = __shfl(adj, 7, 16),
              adj8 = __shfl(adj, 8, 16);

    // wave-max of the 4 group totals
    int mt = max(tot, __shfl_xor(tot, 16));
    mt = max(mt, __shfl_xor(mt, 32));

    float m = 0.f, v0 = 0.f, v1 = 0.f, v2 = 0.f;

    for (int p0 = 0; p0 < mt; p0 += 16) {
        // ---- stage: each group fills up to 16 slots, weights computed once --
        const int j = p0 + zl;
        if (j < tot) {
            const int g1_ = (j >= p1), g2_ = (j >= p2), g3_ = (j >= p3),
                      g4_ = (j >= p4), g5_ = (j >= p5), g6_ = (j >= p6),
                      g7_ = (j >= p7), g8_ = (j >= p8);
            int ad = adj0;
            ad = g1_ ? adj1 : ad;  ad = g2_ ? adj2 : ad;  ad = g3_ ? adj3 : ad;
            ad = g4_ ? adj4 : ad;  ad = g5_ ? adj5 : ad;  ad = g6_ ? adj6 : ad;
            ad = g7_ ? adj7 : ad;  ad = g8_ ? adj8 : ad;
            const int dp = 10 - g1_ - g2_ - 2*g3_ - g4_ - g5_ - 2*g6_ - g7_ - g8_;
            const int idx = j + ad;

            const float4 A = sA[pbase + idx];    // {fx, fy, Zp, d0}
            const float2 B = sB[pbase + idx];    // {d1, d2}
            const float bzf = floorf(A.z - 0.5f);
            const float fz  = A.z - bzf;
            const float wxy = wsel(A.x, dp >> 2) * wsel(A.y, dp & 3);
            const float q0 = 1.5f - fz, q1 = fz - 1.0f, q2 = fz - 0.5f;
            rec[wid][g][zl] =
                make_float4(__int_as_float((int)bzf), A.w, B.x, B.y);
            ws[wid][0][g][zl] = wxy * (0.5f * q0 * q0);
            ws[wid][1][g][zl] = wxy * (0.75f - q1 * q1);
            ws[wid][2][g][zl] = wxy * (0.5f * q2 * q2);
        }
        // ---- accumulate this batch (group-uniform bound) --------------------
        const int cc = min(tot - p0, 16);
        for (int p = 0; p < cc; ++p) {
            const float4 R = rec[wid][g][p];     // 4 distinct banks, no conflict
            const int bz = __float_as_int(R.x);
            const int k  = cz - bz;
            const int ka = min(max(k, 0), 2);
            const float wsv = ws[wid][ka][g][p]; // 12 distinct banks (17-stride)
            const float w = ((unsigned)k <= 2u) ? wsv : 0.0f;
            m  += w;                             // P_MASS = 1
            v0 += w * R.y;
            v1 += w * R.z;
            v2 += w * R.w;
        }
    }

    // flush: lane owns cell (t, cx, cy, cz) -> write-once coalesced stores
    const long gidx = (long)t * CELLS + ((long)col << 7) + cz;
    grids[gidx]      = m;
    gdef[gidx*3 + 0] = v0;
    gdef[gidx*3 + 1] = v1;
    gdef[gidx*3 + 2] = v2;
}

// ---- last-resort fallback: direct global atomics ----------------------------
__global__ void __launch_bounds__(256)
p2g_direct(const float* __restrict__ xs, const float* __restrict__ def,
           float* __restrict__ grids, float* __restrict__ gdef, int N)
{
    const int p = blockIdx.x * blockDim.x + threadIdx.x;
    const int t = blockIdx.y;
    if (p >= N) return;
    const long i = (long)t * N + p;
    const float dx = def[i*3], dy = def[i*3+1], dz = def[i*3+2];
    float fx, fy, fz;
    int3 b = base_cell(xs[i*3], xs[i*3+1], xs[i*3+2], fx, fy, fz);
    float wx[3], wy[3], wz[3];
    wx[0] = 0.5f*(1.5f-fx)*(1.5f-fx); wx[1] = 0.75f-(fx-1.f)*(fx-1.f); wx[2] = 0.5f*(fx-0.5f)*(fx-0.5f);
    wy[0] = 0.5f*(1.5f-fy)*(1.5f-fy); wy[1] = 0.75f-(fy-1.f)*(fy-1.f); wy[2] = 0.5f*(fy-0.5f)*(fy-0.5f);
    wz[0] = 0.5f*(1.5f-fz)*(1.5f-fz); wz[1] = 0.75f-(fz-1.f)*(fz-1.f); wz[2] = 0.5f*(fz-0.5f)*(fz-0.5f);
    const long tbase = (long)t * CELLS;
    #pragma unroll
    for (int ii = 0; ii < 3; ++ii) {
        const long xoff = tbase + (long)(b.x + ii) * (G * G);
        #pragma unroll
        for (int jj = 0; jj < 3; ++jj) {
            const float wij = wx[ii] * wy[jj];
            const long yoff = xoff + (long)(b.y + jj) * G;
            #pragma unroll
            for (int kk = 0; kk < 3; ++kk) {
                const float w = wij * wz[kk];
                const long idx = yoff + (b.z + kk);
                atomicAdd(&grids[idx], w);
                atomicAdd(&gdef[idx*3+0], w * dx);
                atomicAdd(&gdef[idx*3+1], w * dy);
                atomicAdd(&gdef[idx*3+2], w * dz);
            }
        }
    }
}

extern "C" void kernel_launch(void* const* d_in, const int* in_sizes, int n_in,
                              void* d_out, int out_size, void* d_ws, size_t ws_size,
                              hipStream_t stream)
{
    const float* xs  = (const float*)d_in[0];
    const float* def = (const float*)d_in[1];
    float* out = (float*)d_out;

    const int T = (int)(out_size / ((long)CELLS * 4));
    const int N = in_sizes[0] / (3 * T);

    float* grids = out;
    float* gdef  = out + (long)T * CELLS;

    const size_t szA    = (size_t)T * N * sizeof(float4);     // 12.8 MB
    const size_t szB    = (size_t)T * N * sizeof(float2);     //  6.4 MB
    const size_t szArr  = (size_t)T * BUCKETS * sizeof(int);  // 16 MB
    const size_t szSums = (size_t)T * 128 * sizeof(int);
    const size_t need   = szA + szB + szArr + szSums;

    if (ws_size >= need) {
        char* ws = (char*)d_ws;
        float4* sA   = (float4*)ws;  ws += szA;
        float2* sB   = (float2*)ws;  ws += szB;
        int*    arr  = (int*)ws;     ws += szArr;
        int*    sums = (int*)ws;

        hipMemsetAsync(arr, 0, szArr, stream);

        dim3 pgrid((N + 255) / 256, T);
        cell_hist    <<<pgrid, dim3(256), 0, stream>>>(xs, arr, N);
        scan1        <<<dim3(BUCKETS / 4096, T), dim3(256), 0, stream>>>(arr, sums);
        scan2        <<<dim3(T), dim3(128), 0, stream>>>(sums);
        scatter_cells<<<pgrid, dim3(256), 0, stream>>>(xs, def, arr, sums, sA, sB, N);
        // waves = 16384 cols x 2 halves = 32768; 4 waves/block -> 8192 blocks
        gather_cells4<<<dim3(CELLS / 256, T), dim3(256), 0, stream>>>(
            sA, sB, arr, sums, grids, gdef, N);
        return;
    }

    hipMemsetAsync(d_out, 0, (size_t)out_size * sizeof(float), stream);
    dim3 grid((N + 255) / 256, T);
    p2g_direct<<<grid, dim3(256), 0, stream>>>(xs, def, grids, gdef, N);
}